// Round 5
// baseline (373.445 us; speedup 1.0000x reference)
//
#include <hip/hip_runtime.h>
#include <math.h>

#define IMG 512
#define PLANES 96            // 32 N * 3 C
#define XS_W 54              // valid output columns per wave
#define NXS 10               // ceil(512/54)
#define YS_H 64              // output rows per wave
#define NYS 8                // 512/64
#define WPB 4                // waves per block
#define NSLOT 32
#define ACC_STRIDE 16        // doubles per atomic slot (128 B pad)
#define INV_NPIX (1.0 / 25165824.0)

template<int P>
__device__ __forceinline__ void row_step(
    int T, int y0, bool col_ok, int colc, int idx_base,
    const float* __restrict__ p1, const float* __restrict__ p2,
    float& x1, float& x2, float& y1, float& y2,
    const float (&g)[11], float (&A)[5][11],
    bool out_ok, float& sL, float& sC, float& sS)
{
    const int t = T + P;
    // ---- depth-2 prefetch: row t+2 (row index & bounds wave-uniform -> SALU) ----
    float f1 = 0.f, f2 = 0.f;
    {
        const int gy = y0 - 3 + t;               // (y0-5) + (t+2)
        if ((unsigned)gy < IMG) {                // uniform branch: edge rows skip loads
            float l1 = (p1 + gy * IMG)[colc];    // colc clamped -> always in-bounds
            float l2 = (p2 + gy * IMG)[colc];
            f1 = col_ok ? l1 : 0.f;
            f2 = col_ok ? l2 : 0.f;
        }
    }
    // ---- horizontal window via parallel ds_bpermute (DS pipe, beside VALU).
    // idx_base=(lane-5)<<2; negative wrap only affects lanes 0-4 whose outputs
    // are discarded by out_ok; valid lanes (5..58) index strictly in-wave. ----
    float a[11], b[11];
    #pragma unroll
    for (int j = 0; j < 11; ++j) {
        if (j == 5) { a[j] = x1; b[j] = x2; }
        else {
            a[j] = __int_as_float(__builtin_amdgcn_ds_bpermute(idx_base + (j << 2), __float_as_int(x1)));
            b[j] = __int_as_float(__builtin_amdgcn_ds_bpermute(idx_base + (j << 2), __float_as_int(x2)));
        }
    }
    // ---- horizontal 11-tap for 5 quantities (weights in SGPRs) ----
    float H1 = 0.f, H2 = 0.f, H11 = 0.f, H22 = 0.f, H12 = 0.f;
    #pragma unroll
    for (int j = 0; j < 11; ++j) {
        float w = g[j];
        float t1 = w * a[j], t2 = w * b[j];
        H1 += t1; H2 += t2;
        H11 = fmaf(t1, a[j], H11);
        H22 = fmaf(t2, b[j], H22);
        H12 = fmaf(t1, b[j], H12);
    }
    // ---- vertical ring accumulate (statically indexed: t ≡ P mod 11).
    // j=10 OVERWRITES slot P (emitted & dead since previous step) with the
    // g[0] tap of its new output row -> no per-row zeroing needed. ----
    #pragma unroll
    for (int j = 0; j < 11; ++j) {
        const int s = (P + j + 1) % 11;
        float w = g[10 - j];
        if (j == 10) {
            A[0][s] = w * H1;  A[1][s] = w * H2;
            A[2][s] = w * H11; A[3][s] = w * H22; A[4][s] = w * H12;
        } else {
            A[0][s] = fmaf(w, H1,  A[0][s]);
            A[1][s] = fmaf(w, H2,  A[1][s]);
            A[2][s] = fmaf(w, H11, A[2][s]);
            A[3][s] = fmaf(w, H22, A[3][s]);
            A[4][s] = fmaf(w, H12, A[4][s]);
        }
    }
    // ---- emit output row r = t-10 from slot (P+1)%11 (completed at j=0) ----
    const int es = (P + 1) % 11;
    if (t >= 10) {                               // wave-uniform
        float mu1 = A[0][es], mu2 = A[1][es];
        float x11 = A[2][es], x22 = A[3][es], x12 = A[4][es];
        float mu1s = mu1 * mu1, mu2s = mu2 * mu2, mu12 = mu1 * mu2;
        float v1 = x11 - mu1s, v2 = x22 - mu2s, v12 = x12 - mu12;
        float a1 = fabsf(v1), a2 = fabsf(v2);
        float q12 = sqrtf(a1 * a2);
        const float C1 = 1e-4f, C2 = 9e-4f, C3 = 4.5e-4f;
        float eL = __fdividef(2.f * mu12 + C1, mu1s + mu2s + C1);
        float eC = __fdividef(2.f * q12 + C2, a1 + a2 + C2);
        float eS = __fdividef(v12 + C3, q12 + C3);
        if (out_ok) { sL += eL; sC += eC; sS += eS; }
    }
    x1 = y1; x2 = y2; y1 = f1; y2 = f2;
}

// __launch_bounds__(256, 2): min 2 waves/EU -> 256 arch-VGPR budget. The
// default heuristic targeted 8 waves/EU (64 VGPRs) and spilled the 55-reg
// vertical ring to AGPRs (~96 AGPRs, occupancy arithmetic R4: 38% = 3
// waves/SIMD = ~160 total regs/wave), paying 2 accvgpr moves per ring FMA.
__global__ __launch_bounds__(256, 2) void ssim_main(
    const float* __restrict__ img1, const float* __restrict__ img2,
    const float* __restrict__ win, double* __restrict__ acc)
{
    const int lane = threadIdx.x & 63;
    const int wid  = __builtin_amdgcn_readfirstlane(blockIdx.x * WPB + (threadIdx.x >> 6));
    const int plane = wid / (NXS * NYS);
    const int rem   = wid % (NXS * NYS);
    const int ys = rem / NXS, xs = rem % NXS;
    const int x0 = xs * XS_W;
    const int y0 = ys * YS_H;
    const int col = x0 - 5 + lane;
    const bool col_ok = (unsigned)col < IMG;
    const int colc = min(max(col, 0), IMG - 1);  // clamped: safe address when masked
    const bool out_ok = (lane >= 5) && (lane <= 58) && col_ok;
    const int idx_base = (lane - 5) << 2;        // bpermute byte-index base

    // separable 1-D Gaussian from diagonal of 2-D window: w2d[i][i]=g[i]^2
    float g[11];
    #pragma unroll
    for (int j = 0; j < 11; ++j)
        g[j] = __int_as_float(__builtin_amdgcn_readfirstlane(__float_as_int(sqrtf(win[j * 12]))));

    const float* p1 = img1 + (size_t)plane * (IMG * IMG);
    const float* p2 = img2 + (size_t)plane * (IMG * IMG);

    // startup: rows t=0 (gy=y0-5) and t=1 (gy=y0-4)
    float x1 = 0.f, x2 = 0.f, y1 = 0.f, y2 = 0.f;
    {
        int gy = y0 - 5;
        if ((unsigned)gy < IMG) {
            float l1 = (p1 + gy * IMG)[colc], l2 = (p2 + gy * IMG)[colc];
            x1 = col_ok ? l1 : 0.f; x2 = col_ok ? l2 : 0.f;
        }
    }
    {
        int gy = y0 - 4;
        if ((unsigned)gy < IMG) {
            float l1 = (p1 + gy * IMG)[colc], l2 = (p2 + gy * IMG)[colc];
            y1 = col_ok ? l1 : 0.f; y2 = col_ok ? l2 : 0.f;
        }
    }

    float A[5][11];   // init once; steps 0..9 accumulate garbage-free thereafter
    #pragma unroll
    for (int q = 0; q < 5; ++q)
        #pragma unroll
        for (int s = 0; s < 11; ++s) A[q][s] = 0.f;

    float sL = 0.f, sC = 0.f, sS = 0.f;

    #pragma unroll 1
    for (int T = 0; T < 66; T += 11) {           // t = 0..65
        row_step<0>(T, y0, col_ok, colc, idx_base, p1, p2, x1, x2, y1, y2, g, A, out_ok, sL, sC, sS);
        row_step<1>(T, y0, col_ok, colc, idx_base, p1, p2, x1, x2, y1, y2, g, A, out_ok, sL, sC, sS);
        row_step<2>(T, y0, col_ok, colc, idx_base, p1, p2, x1, x2, y1, y2, g, A, out_ok, sL, sC, sS);
        row_step<3>(T, y0, col_ok, colc, idx_base, p1, p2, x1, x2, y1, y2, g, A, out_ok, sL, sC, sS);
        row_step<4>(T, y0, col_ok, colc, idx_base, p1, p2, x1, x2, y1, y2, g, A, out_ok, sL, sC, sS);
        row_step<5>(T, y0, col_ok, colc, idx_base, p1, p2, x1, x2, y1, y2, g, A, out_ok, sL, sC, sS);
        row_step<6>(T, y0, col_ok, colc, idx_base, p1, p2, x1, x2, y1, y2, g, A, out_ok, sL, sC, sS);
        row_step<7>(T, y0, col_ok, colc, idx_base, p1, p2, x1, x2, y1, y2, g, A, out_ok, sL, sC, sS);
        row_step<8>(T, y0, col_ok, colc, idx_base, p1, p2, x1, x2, y1, y2, g, A, out_ok, sL, sC, sS);
        row_step<9>(T, y0, col_ok, colc, idx_base, p1, p2, x1, x2, y1, y2, g, A, out_ok, sL, sC, sS);
        row_step<10>(T, y0, col_ok, colc, idx_base, p1, p2, x1, x2, y1, y2, g, A, out_ok, sL, sC, sS);
    }
    // tail: t = 66..73
    row_step<0>(66, y0, col_ok, colc, idx_base, p1, p2, x1, x2, y1, y2, g, A, out_ok, sL, sC, sS);
    row_step<1>(66, y0, col_ok, colc, idx_base, p1, p2, x1, x2, y1, y2, g, A, out_ok, sL, sC, sS);
    row_step<2>(66, y0, col_ok, colc, idx_base, p1, p2, x1, x2, y1, y2, g, A, out_ok, sL, sC, sS);
    row_step<3>(66, y0, col_ok, colc, idx_base, p1, p2, x1, x2, y1, y2, g, A, out_ok, sL, sC, sS);
    row_step<4>(66, y0, col_ok, colc, idx_base, p1, p2, x1, x2, y1, y2, g, A, out_ok, sL, sC, sS);
    row_step<5>(66, y0, col_ok, colc, idx_base, p1, p2, x1, x2, y1, y2, g, A, out_ok, sL, sC, sS);
    row_step<6>(66, y0, col_ok, colc, idx_base, p1, p2, x1, x2, y1, y2, g, A, out_ok, sL, sC, sS);
    row_step<7>(66, y0, col_ok, colc, idx_base, p1, p2, x1, x2, y1, y2, g, A, out_ok, sL, sC, sS);

    // ---- wave reduction (no barriers), one diluted atomic set per wave ----
    #pragma unroll
    for (int off = 32; off > 0; off >>= 1) {
        sL += __shfl_down(sL, off, 64);
        sC += __shfl_down(sC, off, 64);
        sS += __shfl_down(sS, off, 64);
    }
    if (lane == 0) {
        double* slot = acc + (size_t)(wid & (NSLOT - 1)) * ACC_STRIDE;
        atomicAdd(slot + 0, (double)sL);
        atomicAdd(slot + 1, (double)sC);
        atomicAdd(slot + 2, (double)sS);
    }
}

__global__ void ssim_fin(const double* __restrict__ acc, float* __restrict__ out) {
    int i = threadIdx.x;
    if (i < 3) {
        double s = 0.0;
        for (int k = 0; k < NSLOT; ++k) s += acc[k * ACC_STRIDE + i];
        out[i] = (float)(s * INV_NPIX);
    }
}

extern "C" void kernel_launch(void* const* d_in, const int* in_sizes, int n_in,
                              void* d_out, int out_size, void* d_ws, size_t ws_size,
                              hipStream_t stream) {
    const float* img1 = (const float*)d_in[0];
    const float* img2 = (const float*)d_in[1];
    const float* win  = (const float*)d_in[2];
    float* out = (float*)d_out;
    double* acc = (double*)d_ws;

    hipMemsetAsync(d_ws, 0, NSLOT * ACC_STRIDE * sizeof(double), stream);
    ssim_main<<<(PLANES * NXS * NYS) / WPB, 64 * WPB, 0, stream>>>(img1, img2, win, acc);
    ssim_fin<<<1, 64, 0, stream>>>(acc, out);
}

// Round 6
// 333.310 us; speedup vs baseline: 1.1204x; 1.1204x over previous
//
#include <hip/hip_runtime.h>
#include <math.h>

#define IMG 512
#define PLANES 96            // 32 N * 3 C
#define XS_W 54              // valid output columns per wave
#define NXS 10               // ceil(512/54)
#define YS_H 64              // output rows per wave
#define NYS 8                // 512/64
#define WPB 4                // waves per block
#define NSLOT 32
#define ACC_STRIDE 16        // doubles per atomic slot (128 B pad)
#define INV_NPIX (1.0 / 25165824.0)

typedef float v2f __attribute__((ext_vector_type(2)));

// ws layout: [0, 4096): double acc[NSLOT*ACC_STRIDE]; [4096, 4140): float gw[11]

__global__ void ssim_init(double* __restrict__ acc, float* __restrict__ gwp,
                          const float* __restrict__ win) {
    int i = threadIdx.x;
    if (i < NSLOT * ACC_STRIDE) acc[i] = 0.0;
    // separable 1-D Gaussian from diagonal of 2-D window (ch 0): w2d[i][i]=g[i]^2
    if (i < 11) gwp[i] = sqrtf(win[i * 12]);
}

template<int P>
__device__ __forceinline__ void row_step(
    int T, int y0, bool col_ok,
    const float* __restrict__ p1, const float* __restrict__ p2,
    float& x1, float& x2, const int (&si)[11], const float* __restrict__ g,
    v2f (&Amu)[11], v2f (&Asq)[11], float (&A12)[11],
    bool out_ok, float& sL, float& sC, float& sS)
{
    const int t = T + P;
    // ---- depth-1 prefetch: row t+1 (R2's measured-best load structure) ----
    const int gy_next = y0 - 4 + t;
    float nx1 = 0.f, nx2 = 0.f;
    if (col_ok && (unsigned)gy_next < IMG) {
        int off = gy_next * IMG;
        nx1 = p1[off];
        nx2 = p2[off];
    }
    // ---- horizontal window via parallel ds_bpermute, packed (a,b) pairs ----
    v2f ab[11];
    #pragma unroll
    for (int j = 0; j < 11; ++j) {
        if (j == 5) { ab[j].x = x1; ab[j].y = x2; }
        else {
            ab[j].x = __int_as_float(__builtin_amdgcn_ds_bpermute(si[j], __float_as_int(x1)));
            ab[j].y = __int_as_float(__builtin_amdgcn_ds_bpermute(si[j], __float_as_int(x2)));
        }
    }
    // ---- horizontal 11-tap, packed: (H1,H2) and (H11,H22) via v_pk_fma_f32,
    //      H12 scalar off the pk_mul's lo word. 4 instr/tap vs 7 scalar. ----
    v2f Hmu = {0.f, 0.f}, Hsq = {0.f, 0.f};
    float H12 = 0.f;
    #pragma unroll
    for (int j = 0; j < 11; ++j) {
        float w = g[j];
        v2f w2 = {w, w};
        v2f tt = w2 * ab[j];                         // v_pk_mul_f32
        Hmu = __builtin_elementwise_fma(w2, ab[j], Hmu);  // v_pk_fma_f32
        Hsq = __builtin_elementwise_fma(tt, ab[j], Hsq);  // v_pk_fma_f32
        H12 = fmaf(tt.x, ab[j].y, H12);              // scalar v_fma
    }
    // ---- vertical ring, packed: 3 instr/slot vs 5. j=10 OVERWRITES slot P
    //      (emitted & dead) -> no per-row zeroing (verified correct in R5). ----
    #pragma unroll
    for (int j = 0; j < 11; ++j) {
        const int s = (P + j + 1) % 11;
        float w = g[10 - j];
        v2f w2 = {w, w};
        if (j == 10) {
            Amu[s] = w2 * Hmu;
            Asq[s] = w2 * Hsq;
            A12[s] = w * H12;
        } else {
            Amu[s] = __builtin_elementwise_fma(w2, Hmu, Amu[s]);
            Asq[s] = __builtin_elementwise_fma(w2, Hsq, Asq[s]);
            A12[s] = fmaf(w, H12, A12[s]);
        }
    }
    // ---- emit output row r = t-10 from slot (P+1)%11 ----
    const int es = (P + 1) % 11;
    if (t >= 10) {                                   // wave-uniform
        float mu1 = Amu[es].x, mu2 = Amu[es].y;
        float x11 = Asq[es].x, x22 = Asq[es].y, x12 = A12[es];
        float mu1s = mu1 * mu1, mu2s = mu2 * mu2, mu12 = mu1 * mu2;
        float v1 = x11 - mu1s, v2 = x22 - mu2s, v12 = x12 - mu12;
        float a1 = fabsf(v1), a2 = fabsf(v2);
        float q12 = sqrtf(a1 * a2);
        const float C1 = 1e-4f, C2 = 9e-4f, C3 = 4.5e-4f;
        float eL = __fdividef(2.f * mu12 + C1, mu1s + mu2s + C1);
        float eC = __fdividef(2.f * q12 + C2, a1 + a2 + C2);
        float eS = __fdividef(v12 + C3, q12 + C3);
        if (out_ok) { sL += eL; sC += eC; sS += eS; }
    }
    x1 = nx1; x2 = nx2;
}

// lb(256,4): the empirically best config (R2, 211us main). R4/R5 showed the
// allocator pins ~60 arch VGPRs + AGPR overflow at 3 waves/SIMD regardless
// of bounds; this round cuts VALU instruction count instead (pk-fp32).
__global__ __launch_bounds__(256, 4) void ssim_main(
    const float* __restrict__ img1, const float* __restrict__ img2,
    const float* __restrict__ gwp, double* __restrict__ acc)
{
    const int lane = threadIdx.x & 63;
    const int wid  = blockIdx.x * WPB + (threadIdx.x >> 6);
    const int plane = wid / (NXS * NYS);
    const int rem   = wid % (NXS * NYS);
    const int ys = rem / NXS, xs = rem % NXS;
    const int x0 = xs * XS_W;
    const int y0 = ys * YS_H;
    const int col = x0 - 5 + lane;
    const bool col_ok = (unsigned)col < IMG;
    const bool out_ok = (lane >= 5) && (lane <= 58) && col_ok;

    // weights: thread-uniform loads -> SGPRs
    const float* g = gwp;

    // bpermute byte-indices for lane shifts -5..+5 (loop-invariant)
    int si[11];
    #pragma unroll
    for (int j = 0; j < 11; ++j) si[j] = (lane + j - 5) << 2;

    const float* p1 = img1 + (size_t)plane * (IMG * IMG) + col;
    const float* p2 = img2 + (size_t)plane * (IMG * IMG) + col;

    // load row t=0 (gy = y0-5)
    float x1 = 0.f, x2 = 0.f;
    {
        int gy = y0 - 5;
        if (col_ok && (unsigned)gy < IMG) { x1 = p1[gy * IMG]; x2 = p2[gy * IMG]; }
    }

    v2f Amu[11], Asq[11];
    float A12[11];
    #pragma unroll
    for (int s = 0; s < 11; ++s) {
        Amu[s] = (v2f){0.f, 0.f};
        Asq[s] = (v2f){0.f, 0.f};
        A12[s] = 0.f;
    }

    float sL = 0.f, sC = 0.f, sS = 0.f;

    #pragma unroll 1
    for (int T = 0; T < 66; T += 11) {               // t = 0..65
        row_step<0>(T, y0, col_ok, p1, p2, x1, x2, si, g, Amu, Asq, A12, out_ok, sL, sC, sS);
        row_step<1>(T, y0, col_ok, p1, p2, x1, x2, si, g, Amu, Asq, A12, out_ok, sL, sC, sS);
        row_step<2>(T, y0, col_ok, p1, p2, x1, x2, si, g, Amu, Asq, A12, out_ok, sL, sC, sS);
        row_step<3>(T, y0, col_ok, p1, p2, x1, x2, si, g, Amu, Asq, A12, out_ok, sL, sC, sS);
        row_step<4>(T, y0, col_ok, p1, p2, x1, x2, si, g, Amu, Asq, A12, out_ok, sL, sC, sS);
        row_step<5>(T, y0, col_ok, p1, p2, x1, x2, si, g, Amu, Asq, A12, out_ok, sL, sC, sS);
        row_step<6>(T, y0, col_ok, p1, p2, x1, x2, si, g, Amu, Asq, A12, out_ok, sL, sC, sS);
        row_step<7>(T, y0, col_ok, p1, p2, x1, x2, si, g, Amu, Asq, A12, out_ok, sL, sC, sS);
        row_step<8>(T, y0, col_ok, p1, p2, x1, x2, si, g, Amu, Asq, A12, out_ok, sL, sC, sS);
        row_step<9>(T, y0, col_ok, p1, p2, x1, x2, si, g, Amu, Asq, A12, out_ok, sL, sC, sS);
        row_step<10>(T, y0, col_ok, p1, p2, x1, x2, si, g, Amu, Asq, A12, out_ok, sL, sC, sS);
    }
    // tail: t = 66..73
    row_step<0>(66, y0, col_ok, p1, p2, x1, x2, si, g, Amu, Asq, A12, out_ok, sL, sC, sS);
    row_step<1>(66, y0, col_ok, p1, p2, x1, x2, si, g, Amu, Asq, A12, out_ok, sL, sC, sS);
    row_step<2>(66, y0, col_ok, p1, p2, x1, x2, si, g, Amu, Asq, A12, out_ok, sL, sC, sS);
    row_step<3>(66, y0, col_ok, p1, p2, x1, x2, si, g, Amu, Asq, A12, out_ok, sL, sC, sS);
    row_step<4>(66, y0, col_ok, p1, p2, x1, x2, si, g, Amu, Asq, A12, out_ok, sL, sC, sS);
    row_step<5>(66, y0, col_ok, p1, p2, x1, x2, si, g, Amu, Asq, A12, out_ok, sL, sC, sS);
    row_step<6>(66, y0, col_ok, p1, p2, x1, x2, si, g, Amu, Asq, A12, out_ok, sL, sC, sS);
    row_step<7>(66, y0, col_ok, p1, p2, x1, x2, si, g, Amu, Asq, A12, out_ok, sL, sC, sS);

    // ---- wave reduction (no barriers), one diluted atomic set per wave ----
    #pragma unroll
    for (int off = 32; off > 0; off >>= 1) {
        sL += __shfl_down(sL, off, 64);
        sC += __shfl_down(sC, off, 64);
        sS += __shfl_down(sS, off, 64);
    }
    if (lane == 0) {
        double* slot = acc + (size_t)(wid & (NSLOT - 1)) * ACC_STRIDE;
        atomicAdd(slot + 0, (double)sL);
        atomicAdd(slot + 1, (double)sC);
        atomicAdd(slot + 2, (double)sS);
    }
}

__global__ void ssim_fin(const double* __restrict__ acc, float* __restrict__ out) {
    int i = threadIdx.x;
    if (i < 3) {
        double s = 0.0;
        for (int k = 0; k < NSLOT; ++k) s += acc[k * ACC_STRIDE + i];
        out[i] = (float)(s * INV_NPIX);
    }
}

extern "C" void kernel_launch(void* const* d_in, const int* in_sizes, int n_in,
                              void* d_out, int out_size, void* d_ws, size_t ws_size,
                              hipStream_t stream) {
    const float* img1 = (const float*)d_in[0];
    const float* img2 = (const float*)d_in[1];
    const float* win  = (const float*)d_in[2];
    float* out = (float*)d_out;
    double* acc = (double*)d_ws;
    float* gwp = (float*)((char*)d_ws + NSLOT * ACC_STRIDE * sizeof(double));

    ssim_init<<<1, 512, 0, stream>>>(acc, gwp, win);
    ssim_main<<<(PLANES * NXS * NYS) / WPB, 64 * WPB, 0, stream>>>(img1, img2, gwp, acc);
    ssim_fin<<<1, 64, 0, stream>>>(acc, out);
}